// Round 11
// baseline (181.989 us; speedup 1.0000x reference)
//
#include <hip/hip_runtime.h>
#include <hip/hip_bf16.h>

#define B_ 4
#define T_ 2048
#define H_ 768
#define NH_ 12
#define DH_ 64
#define KQ_ 1024
#define KKV_ 1024

typedef unsigned short u16;
typedef unsigned int u32;
typedef unsigned char u8;
typedef __attribute__((ext_vector_type(8))) short short8;
typedef __attribute__((ext_vector_type(4))) float float4v;
typedef __attribute__((ext_vector_type(4))) u16 ushort4v;

__device__ inline float bf2f(u16 u) {
  union { float f; u32 i; } c; c.i = ((u32)u) << 16; return c.f;
}
__device__ inline u16 f2bf(float f) {
  union { float f; u32 i; } c; c.f = f;
  u32 r = c.i + 0x7FFFu + ((c.i >> 16) & 1u);
  return (u16)(r >> 16);
}
// pack two f32 -> bf16x2 (round-half-up via +0x8000, then byte-perm)
__device__ inline u32 pkh(float lo, float hi) {
  union { float f; u32 i; } a, b; a.f = hi; b.f = lo;
  return __builtin_amdgcn_perm(a.i + 0x8000u, b.i + 0x8000u, 0x07060302u);
}
// async global->LDS, 16B per lane; lds dest = wave-uniform base + lane*16
__device__ __forceinline__ void load16_lds(const u16* g, u16* l) {
  __builtin_amdgcn_global_load_lds(
      (const __attribute__((address_space(1))) void*)g,
      (__attribute__((address_space(3))) void*)l, 16, 0, 0);
}
// per-wave dtype vote on hidden words 0..63 (uniform verdict everywhere)
__device__ __forceinline__ int dtype_is_f32(const void* hidden, int lane) {
  const u32 w = ((const u32*)hidden)[lane];
  const u32 e = (w >> 7) & 0xFFu;
  return (__popcll(__ballot(e >= 100u && e <= 140u)) < 32) ? 1 : 0;
}

// compute one BK=64 tile: wave does M32 x N64 (2x4 acc)
__device__ __forceinline__ void compute_tile(
    const u16* __restrict__ Asb, const u16* __restrict__ Bsb,
    int wm, int wn, int l16, int quad, int swz, float4v (&acc)[2][4])
{
#pragma unroll
  for (int s = 0; s < 2; ++s) {
    short8 af[2], bfr[4];
    const int cg = ((s * 4 + quad) ^ swz) * 8;
#pragma unroll
    for (int i = 0; i < 2; ++i)
      af[i]  = *(const short8*)&Asb[(wm + i * 16 + l16) * 64 + cg];
#pragma unroll
    for (int j = 0; j < 4; ++j)
      bfr[j] = *(const short8*)&Bsb[(wn + j * 16 + l16) * 64 + cg];
#pragma unroll
    for (int i = 0; i < 2; ++i)
#pragma unroll
      for (int j = 0; j < 4; ++j)
        acc[i][j] = __builtin_amdgcn_mfma_f32_16x16x32_bf16(af[i], bfr[j], acc[i][j], 0, 0, 0);
  }
}

// ---------------- fused gather+convert+GEMM ---------------------------------
// C[1024,768] = gather(hidden, idx)[1024,768] x W[768,768]^T + bias.
// 64x128 block tile (1152 blocks = 4.5/CU; 48 KB LDS -> 3 blocks/CU resident
// so inter-block overlap hides the barrier drain). XOR-swizzled dbuf LDS.
// Q pre-scaled by 0.125*log2(e).
__global__ __launch_bounds__(256) void gemm_k(
    const void* __restrict__ hidden,
    const void* __restrict__ Wq, const void* __restrict__ bq,
    const void* __restrict__ Wk, const void* __restrict__ bk,
    const void* __restrict__ Wv, const void* __restrict__ bv,
    const int* __restrict__ qidx, const int* __restrict__ kvidx,
    u16* __restrict__ Qg, u16* __restrict__ Kg, u16* __restrict__ VgT,
    float* __restrict__ vmeanSum)
{
  __shared__ u16 As[2][4096];   // 2 x 8 KB  [64][64]
  __shared__ u16 Bs[2][8192];   // 2 x 16 KB [128][64]

  const int lane = threadIdx.x & 63;
  const int isF32 = dtype_is_f32(hidden, lane);

  const int mat = blockIdx.y, b = blockIdx.z;
  const int mb = blockIdx.x & 15, nb = blockIdx.x >> 4;   // 16 x 6
  const int wave = threadIdx.x >> 6;
  const int quad = lane >> 4, l16 = lane & 15;
  const int Mblk = mb * 64, Nblk = nb * 128;
  const int wm = (wave & 1) * 32, wn = (wave >> 1) * 64;

  const int* idx = (mat == 0) ? qidx : kvidx;
  const void* W  = (mat == 0) ? Wq : (mat == 1) ? Wk : Wv;
  const void* bia= (mat == 0) ? bq : (mat == 1) ? bk : bv;

  const int sr = lane >> 3, ss = lane & 7;
  const int gsw = ss ^ sr;                 // swizzled source col-group
  const int ldsW = wave * 512 + lane * 8;  // elem offset inside j-section

  size_t aoff[2], boff[4];
#pragma unroll
  for (int j = 0; j < 2; ++j) {
    const int rl = wave * 8 + sr + 32 * j;
    const int tok = idx[b * KQ_ + Mblk + rl];
    aoff[j] = ((size_t)b * T_ + tok) * H_ + gsw * 8;
  }
#pragma unroll
  for (int j = 0; j < 4; ++j) {
    const int rl = wave * 8 + sr + 32 * j;
    boff[j] = (size_t)(Nblk + rl) * H_ + gsw * 8;
  }

  float4v acc[2][4];
#pragma unroll
  for (int i = 0; i < 2; ++i)
#pragma unroll
    for (int j = 0; j < 4; ++j) acc[i][j] = (float4v){0.f, 0.f, 0.f, 0.f};

  const int swz = l16 & 7;
  if (isF32) {
    const float* hf = (const float*)hidden;
    const float* wf = (const float*)W;
#pragma unroll
    for (int j = 0; j < 2; ++j) {
      float4 a0 = *(const float4*)(hf + aoff[j]);
      float4 a1 = *(const float4*)(hf + aoff[j] + 4);
      uint4 va = {pkh(a0.x, a0.y), pkh(a0.z, a0.w), pkh(a1.x, a1.y), pkh(a1.z, a1.w)};
      *(uint4*)&As[0][j * 2048 + ldsW] = va;
    }
#pragma unroll
    for (int j = 0; j < 4; ++j) {
      float4 b0 = *(const float4*)(wf + boff[j]);
      float4 b1 = *(const float4*)(wf + boff[j] + 4);
      uint4 vb = {pkh(b0.x, b0.y), pkh(b0.z, b0.w), pkh(b1.x, b1.y), pkh(b1.z, b1.w)};
      *(uint4*)&Bs[0][j * 2048 + ldsW] = vb;
    }
    __syncthreads();
    int p = 0;
    for (int k0 = 0; k0 < H_; k0 += 64) {
      const bool nxt = (k0 + 64 < H_);
      float4 na[2][2], nb2[4][2];
      if (nxt) {
#pragma unroll
        for (int j = 0; j < 2; ++j) {
          na[j][0] = *(const float4*)(hf + aoff[j] + k0 + 64);
          na[j][1] = *(const float4*)(hf + aoff[j] + k0 + 68);
        }
#pragma unroll
        for (int j = 0; j < 4; ++j) {
          nb2[j][0] = *(const float4*)(wf + boff[j] + k0 + 64);
          nb2[j][1] = *(const float4*)(wf + boff[j] + k0 + 68);
        }
      }
      compute_tile(&As[p][0], &Bs[p][0], wm, wn, l16, quad, swz, acc);
      if (nxt) {
#pragma unroll
        for (int j = 0; j < 2; ++j) {
          uint4 va = {pkh(na[j][0].x, na[j][0].y), pkh(na[j][0].z, na[j][0].w),
                      pkh(na[j][1].x, na[j][1].y), pkh(na[j][1].z, na[j][1].w)};
          *(uint4*)&As[p ^ 1][j * 2048 + ldsW] = va;
        }
#pragma unroll
        for (int j = 0; j < 4; ++j) {
          uint4 vb = {pkh(nb2[j][0].x, nb2[j][0].y), pkh(nb2[j][0].z, nb2[j][0].w),
                      pkh(nb2[j][1].x, nb2[j][1].y), pkh(nb2[j][1].z, nb2[j][1].w)};
          *(uint4*)&Bs[p ^ 1][j * 2048 + ldsW] = vb;
        }
      }
      __syncthreads();
      p ^= 1;
    }
  } else {
    const u16* hb = (const u16*)hidden;
    const u16* wb = (const u16*)W;
#pragma unroll
    for (int j = 0; j < 2; ++j)
      load16_lds(hb + aoff[j], &As[0][j * 2048 + wave * 512]);
#pragma unroll
    for (int j = 0; j < 4; ++j)
      load16_lds(wb + boff[j], &Bs[0][j * 2048 + wave * 512]);
    __syncthreads();
    int p = 0;
    for (int k0 = 0; k0 < H_; k0 += 64) {
      if (k0 + 64 < H_) {
#pragma unroll
        for (int j = 0; j < 2; ++j)
          load16_lds(hb + aoff[j] + k0 + 64, &As[p ^ 1][j * 2048 + wave * 512]);
#pragma unroll
        for (int j = 0; j < 4; ++j)
          load16_lds(wb + boff[j] + k0 + 64, &Bs[p ^ 1][j * 2048 + wave * 512]);
      }
      compute_tile(&As[p][0], &Bs[p][0], wm, wn, l16, quad, swz, acc);
      __syncthreads();
      p ^= 1;
    }
  }

  // epilogue
  const int Mbase = Mblk + wm, Nbase = Nblk + wn;
  const float sc = (mat == 0) ? 0.18033688f : 1.0f;   // 0.125 * log2(e)
#pragma unroll
  for (int j = 0; j < 4; ++j) {
    const int n = Nbase + j * 16 + l16;
    const float bfv = isF32 ? ((const float*)bia)[n] : bf2f(((const u16*)bia)[n]);
    if (mat == 2) {        // V column partial sum (for the non-q "mean" rows)
      float s = 8.0f * bfv;
#pragma unroll
      for (int i = 0; i < 2; ++i)
#pragma unroll
        for (int r = 0; r < 4; ++r) s += acc[i][j][r];
      atomicAdd(&vmeanSum[b * H_ + n], s);
    }
#pragma unroll
    for (int i = 0; i < 2; ++i) {
#pragma unroll
      for (int r = 0; r < 4; ++r) {
        const int m = Mbase + i * 16 + quad * 4 + r;
        const float v = (acc[i][j][r] + bfv) * sc;
        if (mat == 0)      Qg[((size_t)b * KQ_  + m) * H_   + n] = f2bf(v);
        else if (mat == 1) Kg[((size_t)b * KKV_ + m) * H_   + n] = f2bf(v);
        else               VgT[((size_t)b * H_  + n) * KKV_ + m] = f2bf(v);
      }
    }
  }
}

// ---------------- fused attention (blocks 0..767) + mean-fill (768..1023) ---
__global__ __launch_bounds__(256) void attn_fill_k(
    const void* __restrict__ hidden,
    const u16* __restrict__ Qg, const u16* __restrict__ Kg,
    const u16* __restrict__ VgT, const int* __restrict__ qidx,
    const float* __restrict__ vmeanSum, void* __restrict__ out)
{
  __shared__ u16 Ks[2][4096];   // [64 kv][64 d], 16B-group slot = g ^ xk(row)
  __shared__ u16 Vs[2][4096];   // [64 d][64 kv], slot = g ^ (row&7)
  __shared__ u8 lmap[32];

  const int lane = threadIdx.x & 63;
  const int isF32 = dtype_is_f32(hidden, lane);

  if (blockIdx.x >= 768) {
    // ---- fill path: non-q token rows get mean(V) --------------------------
    const int fb = blockIdx.x - 768;       // 0..255
    const int b = fb >> 6;
    const int t0 = (fb & 63) * 32;
    const int t = threadIdx.x;
    if (t < 32) lmap[t] = 0;
    __syncthreads();
    for (int i = t; i < KQ_; i += 256) {
      const int d = qidx[b * KQ_ + i] - t0;
      if ((unsigned)d < 32u) lmap[d] = 1;
    }
    __syncthreads();
    float4 vm = {0.f, 0.f, 0.f, 0.f};
    ushort4v ov = {0, 0, 0, 0};
    if (t < 192) {
      vm = ((const float4*)(vmeanSum + b * H_))[t];
      const float r = 1.0f / (float)KKV_;
      vm.x *= r; vm.y *= r; vm.z *= r; vm.w *= r;
      ov = (ushort4v){f2bf(vm.x), f2bf(vm.y), f2bf(vm.z), f2bf(vm.w)};
    }
    for (int r = 0; r < 32; ++r) {
      if (lmap[r]) continue;               // q rows are written by attn
      if (t < 192) {
        const size_t off = ((size_t)b * T_ + t0 + r) * H_;
        if (isF32) ((float4*)((float*)out + off))[t] = vm;
        else       ((ushort4v*)((u16*)out + off))[t] = ov;
      }
    }
    return;
  }

  // ---- attention path ------------------------------------------------------
  const int f = blockIdx.x;              // 0..767, XCD-swizzled
  const int xcd = f & 7, jj = f >> 3;
  const int qt = jj & 15, bhh = jj >> 4;
  const int bh = xcd + 8 * bhh;
  const int b = bh / NH_, h = bh % NH_;

  const int wave = threadIdx.x >> 6;
  const int quad = lane >> 4, l16 = lane & 15;
  const int q0 = qt * 64 + wave * 16;

  const u16* qp = Qg + ((size_t)b * KQ_ + q0 + l16) * H_ + h * DH_ + quad * 8;
  const short8 qf0 = *reinterpret_cast<const short8*>(qp);
  const short8 qf1 = *reinterpret_cast<const short8*>(qp + 32);

  const u16* kslice = Kg + (size_t)b * KKV_ * H_ + h * DH_;
  const u16* vslice = VgT + ((size_t)b * H_ + h * DH_) * KKV_;

  const int sr = lane >> 3;
  const int ss = lane & 7;
  const int ldsbase = wave * 1024;

  const int xk = (l16 & 3) | (((l16 >> 2) & 1) << 2);
  const int xv = l16 & 7;
  const int rb = 8 * (l16 >> 2) + (l16 & 3);   // permuted tile0 row base

  float4v o0 = {0,0,0,0}, o1 = {0,0,0,0}, o2 = {0,0,0,0}, o3 = {0,0,0,0};
  float lacc = 0.f;
  union U8 { short8 s; u32 w[4]; };

#pragma unroll
  for (int inst = 0; inst < 2; ++inst) {
    const int r = wave * 16 + inst * 8 + sr;
    const int gk = ss ^ ((r & 3) | (((r >> 3) & 1) << 2));
    load16_lds(kslice + (size_t)r * H_ + gk * 8, &Ks[0][ldsbase + inst * 512]);
    const int gv = ss ^ (r & 7);
    load16_lds(vslice + (size_t)r * KKV_ + gv * 8, &Vs[0][ldsbase + inst * 512]);
  }
  __syncthreads();

  int p = 0;
  for (int c0 = 0; c0 < KKV_; c0 += 64) {
    if (c0 + 64 < KKV_) {
#pragma unroll
      for (int inst = 0; inst < 2; ++inst) {
        const int r = wave * 16 + inst * 8 + sr;
        const int gk = ss ^ ((r & 3) | (((r >> 3) & 1) << 2));
        load16_lds(kslice + (size_t)(c0 + 64 + r) * H_ + gk * 8,
                   &Ks[p ^ 1][ldsbase + inst * 512]);
        const int gv = ss ^ (r & 7);
        load16_lds(vslice + (size_t)r * KKV_ + c0 + 64 + gv * 8,
                   &Vs[p ^ 1][ldsbase + inst * 512]);
      }
    }
#pragma unroll
    for (int c = 0; c < 2; ++c) {
      const int rt0 = c * 32 + rb;
      short8 k00 = *(const short8*)&Ks[p][rt0 * 64 + ((quad ^ xk) * 8)];
      short8 k01 = *(const short8*)&Ks[p][rt0 * 64 + (((4 + quad) ^ xk) * 8)];
      short8 k10 = *(const short8*)&Ks[p][(rt0 + 4) * 64 + ((quad ^ xk) * 8)];
      short8 k11 = *(const short8*)&Ks[p][(rt0 + 4) * 64 + (((4 + quad) ^ xk) * 8)];
      float4v st0 = {0,0,0,0}, st1 = {0,0,0,0};
      st0 = __builtin_amdgcn_mfma_f32_16x16x32_bf16(k00, qf0, st0, 0, 0, 0);
      st0 = __builtin_amdgcn_mfma_f32_16x16x32_bf16(k01, qf1, st0, 0, 0, 0);
      st1 = __builtin_amdgcn_mfma_f32_16x16x32_bf16(k10, qf0, st1, 0, 0, 0);
      st1 = __builtin_amdgcn_mfma_f32_16x16x32_bf16(k11, qf1, st1, 0, 0, 0);

      float p0[4], p1[4];
#pragma unroll
      for (int r = 0; r < 4; ++r) {
        p0[r] = __builtin_exp2f(st0[r]);
        p1[r] = __builtin_exp2f(st1[r]);
        lacc += p0[r] + p1[r];
      }
      U8 pb;
      pb.w[0] = pkh(p0[0], p0[1]); pb.w[1] = pkh(p0[2], p0[3]);
      pb.w[2] = pkh(p1[0], p1[1]); pb.w[3] = pkh(p1[2], p1[3]);

      const int vs = ((c * 4 + quad) ^ xv) * 8;
      o0 = __builtin_amdgcn_mfma_f32_16x16x32_bf16(
          *(const short8*)&Vs[p][l16 * 64 + vs], pb.s, o0, 0, 0, 0);
      o1 = __builtin_amdgcn_mfma_f32_16x16x32_bf16(
          *(const short8*)&Vs[p][(16 + l16) * 64 + vs], pb.s, o1, 0, 0, 0);
      o2 = __builtin_amdgcn_mfma_f32_16x16x32_bf16(
          *(const short8*)&Vs[p][(32 + l16) * 64 + vs], pb.s, o2, 0, 0, 0);
      o3 = __builtin_amdgcn_mfma_f32_16x16x32_bf16(
          *(const short8*)&Vs[p][(48 + l16) * 64 + vs], pb.s, o3, 0, 0, 0);
    }
    __syncthreads();
    p ^= 1;
  }

  lacc += __shfl_xor(lacc, 16, 64);
  lacc += __shfl_xor(lacc, 32, 64);
  const float rinv = 1.0f / lacc;
  const int token = qidx[b * KQ_ + q0 + l16];
  const size_t obase = ((size_t)b * T_ + token) * H_ + h * DH_ + quad * 4;
  float4v ot[4] = {o0, o1, o2, o3};
#pragma unroll
  for (int dt = 0; dt < 4; ++dt) {
    if (isF32) {
      float4 vv = {ot[dt][0] * rinv, ot[dt][1] * rinv, ot[dt][2] * rinv, ot[dt][3] * rinv};
      *(float4*)((float*)out + obase + dt * 16) = vv;
    } else {
      ushort4v vv = {f2bf(ot[dt][0] * rinv), f2bf(ot[dt][1] * rinv),
                     f2bf(ot[dt][2] * rinv), f2bf(ot[dt][3] * rinv)};
      *(ushort4v*)((u16*)out + obase + dt * 16) = vv;
    }
  }
}

extern "C" void kernel_launch(void* const* d_in, const int* in_sizes, int n_in,
                              void* d_out, int out_size, void* d_ws, size_t ws_size,
                              hipStream_t stream) {
  const void* hidden = d_in[0];
  const void* Wq = d_in[2];
  const void* bq = d_in[3];
  const void* Wk = d_in[4];
  const void* bk = d_in[5];
  const void* Wv = d_in[6];
  const void* bv = d_in[7];
  const int* qidx  = (const int*)d_in[8];
  const int* kvidx = (const int*)d_in[9];

  char* ws = (char*)d_ws;
  const size_t SZ = (size_t)B_ * KQ_ * H_ * sizeof(u16);   // 6,291,456
  u16* Qg         = (u16*)(ws);
  u16* Kg         = (u16*)(ws + SZ);
  u16* VgT        = (u16*)(ws + 2 * SZ);
  float* vmeanSum = (float*)(ws + 3 * SZ);                 // 12,288 B

  hipMemsetAsync(vmeanSum, 0, 12288, stream);
  gemm_k<<<dim3(96, 3, B_), 256, 0, stream>>>(hidden, Wq, bq, Wk, bk, Wv, bv,
                                              qidx, kvidx, Qg, Kg, VgT, vmeanSum);
  attn_fill_k<<<dim3(1024), 256, 0, stream>>>(hidden, Qg, Kg, VgT, qidx,
                                              vmeanSum, d_out);
}